// Round 1
// baseline (123.448 us; speedup 1.0000x reference)
//
#include <hip/hip_runtime.h>

#define C2 2.8853900817779268f  // 2*log2(e)

__device__ __forceinline__ float rcp_fast(float x){ return __builtin_amdgcn_rcpf(x); }
__device__ __forceinline__ float exp2_fast(float x){ return __builtin_amdgcn_exp2f(x); }

// ---------------- prep: w2s = -2*w2, c0 = b2 + sum(w2) ----------------
__global__ __launch_bounds__(512) void prep_kernel(
    const float* __restrict__ w2, const float* __restrict__ b2,
    float* __restrict__ w2s, float* __restrict__ c0)
{
    int t = threadIdx.x;  // 512 threads
    float v = w2[t];
    w2s[t] = -2.0f * v;
    #pragma unroll
    for (int off = 32; off; off >>= 1) v += __shfl_down(v, off, 64);
    __shared__ float part[8];
    if ((t & 63) == 0) part[t >> 6] = v;
    __syncthreads();
    if (t == 0) {
        float s = b2[0];
        #pragma unroll
        for (int i = 0; i < 8; i++) s += part[i];
        *c0 = s;
    }
}

// ---------------- GEMM: C[s,j] = sum_k x[s,k]*W[j,k]  (32x64 tile, 4x4 micro) ----
// FINAL=true: full K, writes EH/EM = exp2(C2*(acc+bias)) directly.
// FINAL=false: K-slice of 256, writes raw partial into P.
template<int KLEN, bool FINAL>
__global__ __launch_bounds__(128) void gemm_kernel(
    const float* __restrict__ x,
    const float* __restrict__ Wh, const float* __restrict__ bh,
    const float* __restrict__ Wm, const float* __restrict__ bm,
    float* __restrict__ EH, float* __restrict__ EM,
    float* __restrict__ P)
{
    int bz = blockIdx.z;
    int mat   = FINAL ? bz : (bz >> 2);
    int slice = FINAL ? 0  : (bz & 3);
    int k0base = slice * KLEN;
    const float* W = mat ? Wm : Wh;
    int s0 = blockIdx.y * 32;
    int j0 = blockIdx.x * 64;
    __shared__ float Xs[32][33];   // +1 pad: scalar reads bank = (row+k)%32
    __shared__ float Ws[64][33];
    int tid = threadIdx.x;
    int tx = tid & 15, ty = tid >> 4;   // tx: 16 col-groups, ty: 8 row-groups
    float acc[4][4] = {};
    for (int kc = 0; kc < KLEN; kc += 32) {
        int k0 = k0base + kc;
        #pragma unroll
        for (int l = 0; l < 2; l++) {                 // Xs: 256 float4 slots
            int slot = tid + l * 128;
            int row = slot >> 3, kq = slot & 7;
            float4 v = *(const float4*)(x + (s0 + row) * 1024 + k0 + kq * 4);
            Xs[row][kq*4+0] = v.x; Xs[row][kq*4+1] = v.y;
            Xs[row][kq*4+2] = v.z; Xs[row][kq*4+3] = v.w;
        }
        #pragma unroll
        for (int l = 0; l < 4; l++) {                 // Ws: 512 float4 slots
            int slot = tid + l * 128;
            int row = slot >> 3, kq = slot & 7;
            float4 v = *(const float4*)(W + (j0 + row) * 1024 + k0 + kq * 4);
            Ws[row][kq*4+0] = v.x; Ws[row][kq*4+1] = v.y;
            Ws[row][kq*4+2] = v.z; Ws[row][kq*4+3] = v.w;
        }
        __syncthreads();
        #pragma unroll 8
        for (int k = 0; k < 32; k++) {
            float a[4], b[4];
            #pragma unroll
            for (int i = 0; i < 4; i++) a[i] = Xs[ty*4+i][k];
            #pragma unroll
            for (int j = 0; j < 4; j++) b[j] = Ws[tx*4+j][k];
            #pragma unroll
            for (int i = 0; i < 4; i++)
                #pragma unroll
                for (int j = 0; j < 4; j++)
                    acc[i][j] = fmaf(a[i], b[j], acc[i][j]);
        }
        __syncthreads();
    }
    if (FINAL) {
        const float* bias = mat ? bm : bh;
        float* O = mat ? EM : EH;
        #pragma unroll
        for (int i = 0; i < 4; i++) {
            int r = s0 + ty*4 + i;
            #pragma unroll
            for (int j = 0; j < 4; j++) {
                int c = j0 + tx*4 + j;
                O[r*512 + c] = exp2_fast(C2 * (acc[i][j] + bias[c]));
            }
        }
    } else {
        float* Pp = P + (size_t)(mat*4 + slice) * (512*512);
        #pragma unroll
        for (int i = 0; i < 4; i++) {
            int r = s0 + ty*4 + i;
            #pragma unroll
            for (int j = 0; j < 4; j++) {
                int c = j0 + tx*4 + j;
                Pp[r*512 + c] = acc[i][j];
            }
        }
    }
}

// ---------------- finalize split-K: EH/EM = exp2(C2*(sum P + bias)) ----------
__global__ __launch_bounds__(256) void finalize_kernel(
    const float* __restrict__ P,
    const float* __restrict__ bh, const float* __restrict__ bm,
    float* __restrict__ EH, float* __restrict__ EM)
{
    int g = blockIdx.x * 256 + threadIdx.x;   // 0..524287
    int mat = g >> 18;
    int idx = g & 262143;
    int col = idx & 511;
    const float* Pp = P + (size_t)mat * 4 * 262144 + idx;
    float s = Pp[0] + Pp[262144] + Pp[2*262144] + Pp[3*262144];
    s += (mat ? bm : bh)[col];
    (mat ? EM : EH)[idx] = exp2_fast(C2 * s);
}

// ---------------- scores: out[h,m] = c0 + sum_d w2s[d] * rcp(1 + EH[h,d]*EM[m,d])
// 32x32 tile, 2 outputs/thread (2 h-rows x 1 m-col), 512 threads, 256 blocks.
__global__ __launch_bounds__(512) void scores_kernel(
    const float* __restrict__ EH, const float* __restrict__ EM,
    const float* __restrict__ w2s, const float* __restrict__ c0,
    float* __restrict__ out)
{
    int m0 = blockIdx.x * 32;
    int h0 = blockIdx.y * 32;
    int tid = threadIdx.x;      // 512
    int tx = tid & 31;          // m column
    int ty = tid >> 5;          // 0..15 -> 2 h rows each
    __shared__ float Hs[32][65];   // +1 pad: bank = (row+d)%32, conflict-free
    __shared__ float Ms[32][65];
    __shared__ float ws_s[64];
    float acc0 = 0.f, acc1 = 0.f;
    for (int d0 = 0; d0 < 512; d0 += 64) {
        {
            int row = tid >> 4;     // 0..31 (16 float4 per 64-wide row)
            int q = tid & 15;
            float4 v = *(const float4*)(EH + (h0 + row) * 512 + d0 + q * 4);
            Hs[row][q*4+0] = v.x; Hs[row][q*4+1] = v.y;
            Hs[row][q*4+2] = v.z; Hs[row][q*4+3] = v.w;
            float4 u = *(const float4*)(EM + (m0 + row) * 512 + d0 + q * 4);
            Ms[row][q*4+0] = u.x; Ms[row][q*4+1] = u.y;
            Ms[row][q*4+2] = u.z; Ms[row][q*4+3] = u.w;
            if (tid < 16) {
                float4 w = *(const float4*)(w2s + d0 + tid * 4);
                ws_s[tid*4+0] = w.x; ws_s[tid*4+1] = w.y;
                ws_s[tid*4+2] = w.z; ws_s[tid*4+3] = w.w;
            }
        }
        __syncthreads();
        #pragma unroll 8
        for (int dk = 0; dk < 64; dk++) {
            float w  = ws_s[dk];
            float em = Ms[tx][dk];
            float e0 = Hs[ty*2+0][dk] * em;
            float e1 = Hs[ty*2+1][dk] * em;
            acc0 = fmaf(w, rcp_fast(e0 + 1.0f), acc0);
            acc1 = fmaf(w, rcp_fast(e1 + 1.0f), acc1);
        }
        __syncthreads();
    }
    float c = *c0;
    out[(h0 + ty*2 + 0) * 512 + m0 + tx] = acc0 + c;
    out[(h0 + ty*2 + 1) * 512 + m0 + tx] = acc1 + c;
}

extern "C" void kernel_launch(void* const* d_in, const int* in_sizes, int n_in,
                              void* d_out, int out_size, void* d_ws, size_t ws_size,
                              hipStream_t stream) {
    const float* x   = (const float*)d_in[0];   // [1,512,1024]
    const float* Wh  = (const float*)d_in[1];   // [512,1024]
    const float* bh  = (const float*)d_in[2];   // [512]
    const float* Wm  = (const float*)d_in[3];   // [512,1024]
    const float* bm  = (const float*)d_in[4];   // [512]
    const float* w2  = (const float*)d_in[5];   // [512]
    const float* b2  = (const float*)d_in[6];   // [1]
    float* out = (float*)d_out;                 // [512,512]

    float* w = (float*)d_ws;
    float* EH  = w;                      // 262144
    float* EM  = w + 262144;             // 262144
    float* w2s = w + 524288;             // 512
    float* c0  = w + 524800;             // 1 (+63 pad)
    float* P   = w + 524864;             // 8*262144 (split-K partials)
    const size_t need_split  = (size_t)(524864 + 8*262144) * 4;
    const size_t need_direct = (size_t)524864 * 4;
    (void)need_direct; (void)in_sizes; (void)n_in; (void)out_size;

    prep_kernel<<<1, 512, 0, stream>>>(w2, b2, w2s, c0);

    if (ws_size >= need_split) {
        // split-K x4: 1024 blocks -> 2048 waves, full occupancy
        gemm_kernel<256, false><<<dim3(8, 16, 8), 128, 0, stream>>>(
            x, Wh, bh, Wm, bm, EH, EM, P);
        finalize_kernel<<<2048, 256, 0, stream>>>(P, bh, bm, EH, EM);
    } else {
        // direct full-K fallback (256 blocks)
        gemm_kernel<1024, true><<<dim3(8, 16, 2), 128, 0, stream>>>(
            x, Wh, bh, Wm, bm, EH, EM, P);
    }

    scores_kernel<<<dim3(16, 16), 512, 0, stream>>>(EH, EM, w2s, c0, out);
}